// Round 10
// baseline (236.633 us; speedup 1.0000x reference)
//
#include <hip/hip_runtime.h>
#include <hip/hip_fp16.h>

#define NB 8
#define NH 56
#define NW 56
#define NHW 3136          // NH*NW
#define NCHW 802816
#define NPIX 25088        // NB*NHW
#define NHP 58            // padded dim
#define EPSV 1e-5f
#define BUFS 20480        // shorts per LDS buffer: Al 4096 | Bl 16384
#define TOFN 451584       // NB*18*NHW floats

typedef float f32x4 __attribute__((ext_vector_type(4)));
typedef __bf16 bf16x8 __attribute__((ext_vector_type(8)));
typedef _Float16 f16x8 __attribute__((ext_vector_type(8)));

__device__ __forceinline__ unsigned short f2b(float f) {   // RNE -> bf16
  unsigned int u = __float_as_uint(f);
  u += 0x7FFFu + ((u >> 16) & 1u);
  return (unsigned short)(u >> 16);
}
__device__ __forceinline__ unsigned short f2h(float f) {   // RNE -> fp16
  return __half_as_ushort(__float2half(f));
}
// barrier WITHOUT vmcnt drain (gemm_off only)
__device__ __forceinline__ void soft_barrier() {
  __builtin_amdgcn_s_waitcnt(0xC07F);   // vmcnt=63, expcnt=7, lgkmcnt=0
  __builtin_amdgcn_s_barrier();
}
// async global->LDS DMA, 16B per lane; LDS dest = wave-uniform base + lane*16
__device__ __forceinline__ void dma16(const unsigned short* g, unsigned short* l) {
  __builtin_amdgcn_global_load_lds(
      (const __attribute__((address_space(1))) unsigned int*)g,
      (__attribute__((address_space(3))) unsigned int*)l,
      16, 0, 0);
}
// packed fp16 bilinear: w00*c00 + w01*c01 + w10*c10 + w11*c11 (2 lanes/op)
__device__ __forceinline__ unsigned int bil2(
    unsigned int c00, unsigned int c01, unsigned int c10, unsigned int c11,
    __half2 W00, __half2 W01, __half2 W10, __half2 W11) {
  __half2 v = __hmul2(W00, *(__half2*)&c00);
  v = __hfma2(W01, *(__half2*)&c01, v);
  v = __hfma2(W10, *(__half2*)&c10, v);
  v = __hfma2(W11, *(__half2*)&c11, v);
  return *(unsigned int*)&v;
}

// ---------------------------------------------------------------------------
// P0: zero the 1px borders of xbp and t1b + zero tof
// ---------------------------------------------------------------------------
__global__ __launch_bounds__(256) void clear_borders(
    unsigned short* __restrict__ xbp, unsigned short* __restrict__ t1b,
    float* __restrict__ tof)
{
  int i = blockIdx.x*256 + threadIdx.x;        // 58368 exact
  int q = i & 31; int pid = i >> 5;
  int b = pid / 228, j = pid % 228;
  int y, x;
  if (j < 58)       { y = 0;  x = j; }
  else if (j < 116) { y = 57; x = j - 58; }
  else { int jj = j - 116; y = 1 + (jj >> 1); x = (jj & 1) * 57; }
  size_t addr = ((size_t)(b*NHP + y)*NHP + x)*256 + q*8;
  uint4 z = make_uint4(0u,0u,0u,0u);
  *(uint4*)(xbp + addr) = z;
  *(uint4*)(t1b + addr) = z;
  int zi = i*8;                                // 56448*8 = 451584 exact
  if (zi < TOFN) {
    *(float4*)(tof + zi)     = make_float4(0.f,0.f,0.f,0.f);
    *(float4*)(tof + zi + 4) = make_float4(0.f,0.f,0.f,0.f);
  }
}

// ---------------------------------------------------------------------------
// P1: x NCHW fp32 -> xbp padded NHWC bf16 (interior only)
// ---------------------------------------------------------------------------
__global__ __launch_bounds__(256) void prep_x(
    const float* __restrict__ x, unsigned short* __restrict__ xbp)
{
  __shared__ float T[64][65];
  const int pxt  = blockIdx.x * 64;       // never crosses b (3136 = 49*64)
  const int cg   = blockIdx.y * 64;
  const int b    = pxt / NHW;
  const int rem0 = pxt % NHW;
  const int t    = threadIdx.x;
  const int pl   = t & 63;
  const int c0   = t >> 6;
  const float* src = x + (size_t)b*NCHW + rem0;
  #pragma unroll
  for (int it = 0; it < 16; ++it) {
    int c = c0 + it*4;
    T[c][pl] = src[(size_t)(cg + c)*NHW + pl];
  }
  __syncthreads();
  const int pr = t >> 5;
  const int cp = t & 31;
  #pragma unroll
  for (int it = 0; it < 8; ++it) {
    int pxl = pr + it*8;
    int rem = rem0 + pxl;
    int ho = rem / NW, wo = rem % NW;
    unsigned int pk = ((unsigned int)f2b(T[cp*2+1][pxl]) << 16) | (unsigned int)f2b(T[cp*2][pxl]);
    *(unsigned int*)(xbp + ((size_t)(b*NHP + ho + 1)*NHP + (wo + 1))*256 + cg + cp*2) = pk;
  }
}

// ---------------------------------------------------------------------------
// P2: all three weight preps in ONE kernel
// w1p: bf16 (conv1);  w2p, w3p: fp16 (deform/off use fp16 MFMA)
// ---------------------------------------------------------------------------
__global__ __launch_bounds__(256) void prep_w_all(
    const float* __restrict__ w1, const float* __restrict__ w2,
    const float* __restrict__ ow,
    unsigned short* __restrict__ w1p, unsigned short* __restrict__ w2p,
    unsigned short* __restrict__ w3p)
{
  int i = blockIdx.x*256 + threadIdx.x;    // 1253376 exact (4896 blocks)
  if (i < 589824) {
    int co = i / 2304, r = i % 2304, k = r >> 8, ci = r & 255;
    w1p[i] = f2b(w1[((size_t)co*256 + ci)*9 + k]);
  } else if (i < 1179648) {
    int j = i - 589824;
    int co = j / 2304, r = j % 2304, k = r >> 8, ci = r & 255;
    w2p[j] = f2h(w2[((size_t)co*256 + ci)*9 + k]);
  } else {
    int j = i - 1179648;                   // < 73728
    int co = j / 2304, r = j % 2304, k = r >> 8, ci = r & 255;
    w3p[j] = (co < 18) ? f2h(ow[((size_t)co*256 + ci)*9 + k]) : (unsigned short)0;
  }
}

// ---------------------------------------------------------------------------
// GEMM1: conv3x3 + BN + ReLU -> t1b padded NHWC fp16
// BM=64 BN=256 BK=64; 256 thr = 4 waves, WAVE TILE 64x64 (mt=4, nt=4):
// zero duplicate fragment reads -> LDS reads 96->64KB/round. Full DMA staging,
// LDS dbuf, 1 __syncthreads/round; grid 392, batch-per-XCD swizzle.
// ---------------------------------------------------------------------------
__global__ __launch_bounds__(256, 2) void gemm_conv1(
    const unsigned short* __restrict__ xbp, const unsigned short* __restrict__ w1p,
    const float* __restrict__ gam, const float* __restrict__ bet,
    const float* __restrict__ mu,  const float* __restrict__ var,
    unsigned short* __restrict__ t1b)
{
  __shared__ unsigned short SMEM[2*BUFS];    // 80KB: two of (Al 4096 | Bl 16384)

  const int bx   = blockIdx.x;
  const int nbx  = (bx & 7)*49 + (bx >> 3);   // 392 = 8*49, batch-per-XCD
  const int m0   = nbx * 64;
  const int t    = threadIdx.x;
  const int lane = t & 63;
  const int wv   = t >> 6;       // 0..3 = N group
  const int quad = lane >> 4;
  const int l15  = lane & 15;

  // A DMA: 8KB = 2 calls/wave (8 rows each). lane -> row r0/r1, seg = lane&7
  const int lrow = lane >> 3;            // 0..7
  const int lseg = lane & 7;
  const int r0 = wv*16 + lrow;           // call 0 rows
  const int r1 = r0 + 8;                 // call 1 rows
  unsigned int pbA0, pbA1;
  {
    int p0 = m0 + r0, b0 = p0 / NHW, rm0 = p0 % NHW;
    pbA0 = ((unsigned int)(b0*NHP + rm0/NW)*NHP + rm0%NW)*256u
         + (unsigned int)((lseg ^ (r0 & 7))*8);
    int p1 = m0 + r1, b1 = p1 / NHW, rm1 = p1 % NHW;
    pbA1 = ((unsigned int)(b1*NHP + rm1/NW)*NHP + rm1%NW)*256u
         + (unsigned int)((lseg ^ (r1 & 7))*8);
  }
  // B DMA: 32KB = 8 calls/wave; wave w covers rows w*64..w*64+63
  const int rowB0 = wv*64 + lrow;
  const unsigned int bswz = (unsigned int)((lseg ^ lrow)*8);

  f32x4 acc[4][4];
  #pragma unroll
  for (int i = 0; i < 4; ++i)
    #pragma unroll
    for (int j = 0; j < 4; ++j) acc[i][j] = (f32x4)(0.f);

  {   // prologue: DMA r=0 into buf0
    dma16(xbp + pbA0, &SMEM[(wv*2    )*512]);
    dma16(xbp + pbA1, &SMEM[(wv*2 + 1)*512]);
    #pragma unroll
    for (int j = 0; j < 8; ++j)
      dma16(w1p + (size_t)(rowB0 + j*8)*2304 + bswz, &SMEM[4096 + (wv*8 + j)*512]);
    __syncthreads();
  }

  for (int r = 0; r < 36; ++r) {
    unsigned short* Ac = SMEM + (r & 1)*BUFS;
    unsigned short* Bc = Ac + 4096;
    unsigned short* An = SMEM + ((r + 1) & 1)*BUFS;
    unsigned short* Bn = An + 4096;
    {   // DMA r+1 into next buffer (in flight across the MFMA phase)
      const int rn = (r < 35) ? r + 1 : 35;
      const int kn = rn >> 2, cicn = rn & 3;
      const int kyn = kn/3, kxn = kn - kyn*3;
      const unsigned int koff = (unsigned int)((kyn*NHP + kxn)*256 + cicn*64);
      dma16(xbp + pbA0 + koff, &An[(wv*2    )*512]);
      dma16(xbp + pbA1 + koff, &An[(wv*2 + 1)*512]);
      const unsigned int rb = (unsigned int)(rn*64);
      #pragma unroll
      for (int j = 0; j < 8; ++j)
        dma16(w1p + (size_t)(rowB0 + j*8)*2304 + rb + bswz, &Bn[(wv*8 + j)*512]);
    }
    // MFMA from current buffer: wave tile 64x64 (4 A frags x 4 B frags)
    #pragma unroll
    for (int kk = 0; kk < 2; ++kk) {
      const int s8 = (kk*4 + quad) ^ (l15 & 7);
      bf16x8 af[4], bfr[4];
      #pragma unroll
      for (int mt = 0; mt < 4; ++mt)
        af[mt] = *(const bf16x8*)(&Ac[(mt*16 + l15)*64 + s8*8]);
      #pragma unroll
      for (int nt = 0; nt < 4; ++nt)
        bfr[nt] = *(const bf16x8*)(&Bc[(wv*64 + nt*16 + l15)*64 + s8*8]);
      #pragma unroll
      for (int mt = 0; mt < 4; ++mt)
        #pragma unroll
        for (int nt = 0; nt < 4; ++nt)
          acc[mt][nt] = __builtin_amdgcn_mfma_f32_16x16x32_bf16(af[mt], bfr[nt], acc[mt][nt], 0, 0, 0);
    }
    __syncthreads();   // drains DMA (vmcnt 0) + makes next buffer visible
  }

  // epilogue: BN+ReLU -> per-wave bounce (64px x 72 shorts) -> padded t1b (fp16)
  unsigned short* Sw = SMEM + wv*4608;    // 4*4608 = 18432 shorts = 36.9KB
  #pragma unroll
  for (int nt = 0; nt < 4; ++nt) {
    const int co = wv*64 + nt*16 + l15;
    const float inv  = gam[co] * rsqrtf(var[co] + EPSV);
    const float beta = bet[co] - mu[co]*inv;
    #pragma unroll
    for (int mt = 0; mt < 4; ++mt) {
      #pragma unroll
      for (int rr = 0; rr < 4; ++rr) {
        const int pxl = mt*16 + quad*4 + rr;
        float val = acc[mt][nt][rr]*inv + beta;
        val = val > 0.f ? val : 0.f;
        Sw[pxl*72 + nt*16 + l15] = f2h(val);
      }
    }
  }
  #pragma unroll
  for (int i = 0; i < 8; ++i) {
    const int pxl = (lane >> 3) + 8*i;    // 0..63
    const int sc  = lane & 7;
    uint4 q = *(const uint4*)(&Sw[pxl*72 + sc*8]);
    const int pg = m0 + pxl;
    const int bb = pg / NHW, rm = pg % NHW;
    const int hh = rm / NW, ww = rm % NW;
    *(uint4*)(t1b + ((size_t)(bb*NHP + hh + 1)*NHP + ww + 1)*256 + wv*64 + sc*8) = q;
  }
}

// ---------------------------------------------------------------------------
// GEMM-OFF: offset conv (fp16 operands), split-K x4, atomicAdd into toff
// (unchanged, verified r9)
// ---------------------------------------------------------------------------
__global__ __launch_bounds__(256, 8) void gemm_off(
    const unsigned short* __restrict__ t1b, const unsigned short* __restrict__ w3p,
    const float* __restrict__ ob, float* __restrict__ toff)
{
  __shared__ unsigned short Al[4096];   // 64x64
  __shared__ unsigned short Bl[2048];   // 32x64

  const int bx  = blockIdx.x;
  const int nbx = (bx & 7)*49 + (bx >> 3);
  const int m0  = nbx * 64;
  const int kc = blockIdx.y;            // K chunk 0..3
  const int t    = threadIdx.x;
  const int lane = t & 63;
  const int wv   = t >> 6;
  const int quad = lane >> 4;
  const int l15  = lane & 15;

  const int arow = t >> 2;      // 0..63
  const int as4  = t & 3;
  const int axor = arow & 7;
  const int pxa  = m0 + arow;
  const int ba   = pxa / NHW, rema = pxa % NHW;
  const unsigned int pbase = ((unsigned int)(ba*NHP + rema/NW)*NHP + rema%NW)*256u;

  const int brow = t >> 3;      // 0..31
  const int bs   = t & 7;

  f32x4 acc[2];
  #pragma unroll
  for (int nt = 0; nt < 2; ++nt) {
    float init = 0.f;
    if (kc == 0) { int co = nt*16 + l15; init = (co < 18) ? ob[co] : 0.f; }
    acc[nt] = (f32x4)(init);
  }

  uint4 pA0, pA1, pB;
  {   // prefetch first round r = kc*9
    const int r = kc*9, k = r >> 2, cic = r & 3;
    const int ky = k/3, kx = k - ky*3;
    const unsigned int base = pbase + (unsigned int)((ky*NHP + kx)*256 + cic*64);
    pA0 = *(const uint4*)(t1b + base + as4*8);
    pA1 = *(const uint4*)(t1b + base + (as4+4)*8);
    pB  = *(const uint4*)(w3p + (size_t)brow*2304 + r*64 + bs*8);
  }

  for (int rr = 0; rr < 9; ++rr) {
    const int r = kc*9 + rr;
    __syncthreads();
    *(uint4*)(&Al[arow*64 + ((as4     ^ axor)*8)]) = pA0;
    *(uint4*)(&Al[arow*64 + (((as4+4) ^ axor)*8)]) = pA1;
    *(uint4*)(&Bl[brow*64 + ((bs ^ (brow & 7))*8)]) = pB;
    {
      const int rn = (rr < 8) ? r + 1 : r;
      const int kn = rn >> 2, cicn = rn & 3;
      const int kyn = kn/3, kxn = kn - kyn*3;
      const unsigned int base = pbase + (unsigned int)((kyn*NHP + kxn)*256 + cicn*64);
      pA0 = *(const uint4*)(t1b + base + as4*8);
      pA1 = *(const uint4*)(t1b + base + (as4+4)*8);
      pB  = *(const uint4*)(w3p + (size_t)brow*2304 + rn*64 + bs*8);
    }
    soft_barrier();
    #pragma unroll
    for (int kk = 0; kk < 2; ++kk) {
      const int s8 = (kk*4 + quad) ^ (l15 & 7);
      f16x8 af = *(const f16x8*)(&Al[(wv*16 + l15)*64 + s8*8]);
      #pragma unroll
      for (int nt = 0; nt < 2; ++nt) {
        f16x8 bfr = *(const f16x8*)(&Bl[(nt*16 + l15)*64 + s8*8]);
        acc[nt] = __builtin_amdgcn_mfma_f32_16x16x32_f16(af, bfr, acc[nt], 0, 0, 0);
      }
    }
  }
  #pragma unroll
  for (int nt = 0; nt < 2; ++nt) {
    const int co = nt*16 + l15;
    if (co < 18) {
      #pragma unroll
      for (int rr2 = 0; rr2 < 4; ++rr2) {
        const int pg = m0 + wv*16 + quad*4 + rr2;
        const int bb = pg / NHW, rm = pg % NHW;
        atomicAdd(&toff[(size_t)bb*(18*NHW) + (size_t)co*NHW + rm], acc[nt][rr2]);
      }
    }
  }
}

// ---------------------------------------------------------------------------
// GEMM2: deform_conv + BN + residual + ReLU -> out NCHW fp32
// BM=64 BN=256 BK=64; 256 thr = 4 waves, WAVE TILE 64x64 (zero duplicate
// B-fragment reads). B via DMA (pre-swizzled src), corners via VGPR gather
// (1 row/thread, 2 segs) + packed fp16 bilinear. LDS dbuf, 1 sync/round.
// ---------------------------------------------------------------------------
__global__ __launch_bounds__(256, 2) void gemm_deform(
    const unsigned short* __restrict__ t1b, const unsigned short* __restrict__ w2p,
    const float* __restrict__ toff, const float* __restrict__ xres,
    const float* __restrict__ gam, const float* __restrict__ bet,
    const float* __restrict__ mu,  const float* __restrict__ var,
    float* __restrict__ outp)
{
  __shared__ unsigned short SMEM[2*BUFS];    // 80KB

  const int bid  = blockIdx.x;
  const int nb   = (bid & 7)*49 + (bid >> 3);   // 392 = 8*49
  const int m0   = nb * 64;
  const int t    = threadIdx.x;
  const int lane = t & 63;
  const int wv   = t >> 6;       // 0..3 = N group
  const int quad = lane >> 4;
  const int l15  = lane & 15;

  // corner gather mapping: 1 row/thread, 2 segs (s2, s2+1)
  const int srow = t >> 2;       // 0..63
  const int s2   = (t & 3)*2;    // 0,2,4,6
  const int sxor = srow & 7;
  const int px   = m0 + srow;
  const int b    = px / NHW, rem = px % NHW;
  const int ho   = rem / NW, wo = rem % NW;
  const int obb  = b*(18*NHW) + rem;
  const unsigned int prowb = (unsigned int)(b*NHP);

  // B DMA mapping: 8 calls/wave, wave w covers rows w*64..w*64+63
  const int lrow = lane >> 3;
  const int lseg = lane & 7;
  const int rowB0 = wv*64 + lrow;
  const unsigned int bswz = (unsigned int)((lseg ^ lrow)*8);

  f32x4 acc[4][4];
  #pragma unroll
  for (int i = 0; i < 4; ++i)
    #pragma unroll
    for (int j = 0; j < 4; ++j) acc[i][j] = (f32x4)(0.f);

  // bilinear coord state for the k being issued (o* include s2*8)
  unsigned int o00, o01, o10, o11;
  __half2 W00, W01, W10, W11;
#define COORDS(KK) {                                                   \
    const int ky_ = (KK)/3, kx_ = (KK) - ky_*3;                        \
    const float offy = toff[obb + (KK)*NHW];                           \
    const float offx = toff[obb + (9+(KK))*NHW];                       \
    const float yf = (float)(ho - 1 + ky_) + offy;                     \
    const float xf = (float)(wo - 1 + kx_) + offx;                     \
    const float y0f = floorf(yf), x0f = floorf(xf);                    \
    const float ty = yf - y0f,   tx = xf - x0f;                        \
    const int y0p = (int)y0f + 1, x0p = (int)x0f + 1;                  \
    const int cy0 = min(max(y0p,   0), NHP-1);                         \
    const int cy1 = min(max(y0p+1, 0), NHP-1);                         \
    const int cx0 = min(max(x0p,   0), NHP-1);                         \
    const int cx1 = min(max(x0p+1, 0), NHP-1);                         \
    W00 = __float2half2_rn((1.f-ty)*(1.f-tx));                         \
    W01 = __float2half2_rn((1.f-ty)*tx);                               \
    W10 = __float2half2_rn(ty*(1.f-tx));                               \
    W11 = __float2half2_rn(ty*tx);                                     \
    o00 = ((prowb + cy0)*NHP + cx0)*256u + s2*8u;                      \
    o01 = ((prowb + cy0)*NHP + cx1)*256u + s2*8u;                      \
    o10 = ((prowb + cy1)*NHP + cx0)*256u + s2*8u;                      \
    o11 = ((prowb + cy1)*NHP + cx1)*256u + s2*8u;                      \
  }

// packed-fp16 bilinear of 8 corner uint4 -> two uint4 -> LDS (swizzled segs)
#define PACKW(DST) {                                                            \
    uint4 ra, rb2;                                                              \
    ra.x  = bil2(c00a.x, c01a.x, c10a.x, c11a.x, W00, W01, W10, W11);           \
    ra.y  = bil2(c00a.y, c01a.y, c10a.y, c11a.y, W00, W01, W10, W11);           \
    ra.z  = bil2(c00a.z, c01a.z, c10a.z, c11a.z, W00, W01, W10, W11);           \
    ra.w  = bil2(c00a.w, c01a.w, c10a.w, c11a.w, W00, W01, W10, W11);           \
    rb2.x = bil2(c00b.x, c01b.x, c10b.x, c11b.x, W00, W01, W10, W11);           \
    rb2.y = bil2(c00b.y, c01b.y, c10b.y, c11b.y, W00, W01, W10, W11);           \
    rb2.z = bil2(c00b.z, c01b.z, c10b.z, c11b.z, W00, W01, W10, W11);           \
    rb2.w = bil2(c00b.w, c01b.w, c10b.w, c11b.w, W00, W01, W10, W11);           \
    *(uint4*)(&(DST)[srow*64 + ((s2     ^ sxor)*8)]) = ra;                      \
    *(uint4*)(&(DST)[srow*64 + (((s2+1) ^ sxor)*8)]) = rb2;                     \
  }

#define ISSUEC(RN) {                                                           \
    const unsigned int cio_ = (unsigned int)(((RN) & 3)*64);                   \
    c00a = *(const uint4*)(t1b + o00 + cio_);                                  \
    c00b = *(const uint4*)(t1b + o00 + cio_ + 8);                              \
    c01a = *(const uint4*)(t1b + o01 + cio_);                                  \
    c01b = *(const uint4*)(t1b + o01 + cio_ + 8);                              \
    c10a = *(const uint4*)(t1b + o10 + cio_);                                  \
    c10b = *(const uint4*)(t1b + o10 + cio_ + 8);                              \
    c11a = *(const uint4*)(t1b + o11 + cio_);                                  \
    c11b = *(const uint4*)(t1b + o11 + cio_ + 8);                              \
  }

  uint4 c00a, c00b, c01a, c01b, c10a, c10b, c11a, c11b;

  COORDS(0);
  {   // prologue: corners(0) -> pack into buf0; DMA B(0) -> buf0; issue corners(1)
    ISSUEC(0);
    #pragma unroll
    for (int j = 0; j < 8; ++j)
      dma16(w2p + (size_t)(rowB0 + j*8)*2304 + bswz, &SMEM[4096 + (wv*8 + j)*512]);
    PACKW(SMEM);
    ISSUEC(1);
    __syncthreads();
  }

  for (int r = 0; r < 36; ++r) {
    unsigned short* Ac = SMEM + (r & 1)*BUFS;
    unsigned short* Bc = Ac + 4096;
    unsigned short* An = SMEM + ((r + 1) & 1)*BUFS;
    unsigned short* Bn = An + 4096;
    // pack prefetched corners(r+1) -> next A buffer (weights for k=(r+1)>>2 live)
    PACKW(An);
    {   // DMA B(r+1) -> next B buffer
      const int rnB = (r < 35) ? r + 1 : 35;
      const unsigned int rb = (unsigned int)(rnB*64);
      #pragma unroll
      for (int j = 0; j < 8; ++j)
        dma16(w2p + (size_t)(rowB0 + j*8)*2304 + rb + bswz, &Bn[(wv*8 + j)*512]);
    }
    // coords for the k of round r+2 (AFTER pack used old weights)
    if ((r & 3) == 2 && r < 34) COORDS((r + 2) >> 2);
    {   // issue corners(r+2) (latency hidden by MFMA + drained at barrier)
      const int rn = (r < 34) ? r + 2 : 35;
      ISSUEC(rn);
    }
    // MFMA from current buffer: wave tile 64x64 (fp16)
    #pragma unroll
    for (int kk = 0; kk < 2; ++kk) {
      const int s8 = (kk*4 + quad) ^ (l15 & 7);
      f16x8 af[4], bfr[4];
      #pragma unroll
      for (int mt = 0; mt < 4; ++mt)
        af[mt] = *(const f16x8*)(&Ac[(mt*16 + l15)*64 + s8*8]);
      #pragma unroll
      for (int nt = 0; nt < 4; ++nt)
        bfr[nt] = *(const f16x8*)(&Bc[(wv*64 + nt*16 + l15)*64 + s8*8]);
      #pragma unroll
      for (int mt = 0; mt < 4; ++mt)
        #pragma unroll
        for (int nt = 0; nt < 4; ++nt)
          acc[mt][nt] = __builtin_amdgcn_mfma_f32_16x16x32_f16(af[mt], bfr[nt], acc[mt][nt], 0, 0, 0);
    }
    __syncthreads();   // drains B-DMA + corner loads, publishes next buffers
  }
#undef ISSUEC
#undef PACKW
#undef COORDS

  // epilogue: per-wave f32 bounce (32px x 33) x 2 row-halves -> coalesced NCHW
  float* Sl = (float*)SMEM + wv*1056;    // 4 waves x 4224B = 16.9KB
  const int pxl_r = lane & 31;
  const int csel  = lane >> 5;
  #pragma unroll
  for (int mh = 0; mh < 2; ++mh) {       // row halves: px 0..31, 32..63
    const int pg    = m0 + mh*32 + pxl_r;
    const int bo    = pg / NHW, remo = pg % NHW;
    const size_t obase = (size_t)bo*NCHW + remo;
    #pragma unroll
    for (int h = 0; h < 2; ++h) {        // col halves of the wave's 64 cols
      #pragma unroll
      for (int nt2 = 0; nt2 < 2; ++nt2) {
        const int nt = h*2 + nt2;
        #pragma unroll
        for (int mt2 = 0; mt2 < 2; ++mt2) {
          #pragma unroll
          for (int rr = 0; rr < 4; ++rr) {
            const int pxl = mt2*16 + quad*4 + rr;
            Sl[pxl*33 + nt2*16 + l15] = acc[mh*2 + mt2][nt][rr];
          }
        }
      }
      #pragma unroll
      for (int j = 0; j < 16; ++j) {
        const int col = csel*16 + j;
        const int co  = wv*64 + h*32 + col;
        const float inv  = gam[co] * rsqrtf(var[co] + EPSV);
        const float beta = bet[co] - mu[co]*inv;
        const size_t off = obase + (size_t)co*NHW;
        float val = Sl[pxl_r*33 + col];
        float o = val*inv + beta + xres[off];
        outp[off] = o > 0.f ? o : 0.f;
      }
    }
  }
}

extern "C" void kernel_launch(void* const* d_in, const int* in_sizes, int n_in,
                              void* d_out, int out_size, void* d_ws, size_t ws_size,
                              hipStream_t stream) {
  const float* x   = (const float*)d_in[0];
  const float* w1  = (const float*)d_in[1];
  const float* g1  = (const float*)d_in[2];
  const float* b1  = (const float*)d_in[3];
  const float* m1  = (const float*)d_in[4];
  const float* v1  = (const float*)d_in[5];
  const float* ow  = (const float*)d_in[6];
  const float* ob  = (const float*)d_in[7];
  const float* w2  = (const float*)d_in[8];
  const float* g2  = (const float*)d_in[9];
  const float* b2  = (const float*)d_in[10];
  const float* m2  = (const float*)d_in[11];
  const float* v2  = (const float*)d_in[12];
  float* out = (float*)d_out;

  const size_t PADSZ = (size_t)NB*NHP*NHP*256;
  unsigned short* xbp = (unsigned short*)d_ws;
  unsigned short* t1b = xbp + PADSZ;
  float*          tof = (float*)(t1b + PADSZ);
  unsigned short* w1p = (unsigned short*)(tof + (size_t)NB*18*NHW);
  unsigned short* w2p = w1p + (size_t)589824;
  unsigned short* w3p = w2p + (size_t)589824;

  clear_borders<<<228, 256, 0, stream>>>(xbp, t1b, tof);
  dim3 gp(392, 4, 1);
  prep_x<<<gp, 256, 0, stream>>>(x, xbp);
  prep_w_all<<<4896, 256, 0, stream>>>(w1, w2, ow, w1p, w2p, w3p);

  gemm_conv1<<<392, 256, 0, stream>>>(xbp, w1p, g1, b1, m1, v1, t1b);
  dim3 go(392, 4, 1);
  gemm_off<<<go, 256, 0, stream>>>(t1b, w3p, ob, tof);
  gemm_deform<<<392, 256, 0, stream>>>(t1b, w2p, tof, x, g2, b2, m2, v2, out);
}

// Round 11
// 223.641 us; speedup vs baseline: 1.0581x; 1.0581x over previous
//
#include <hip/hip_runtime.h>
#include <hip/hip_fp16.h>

#define NB 8
#define NH 56
#define NW 56
#define NHW 3136          // NH*NW
#define NCHW 802816
#define NPIX 25088        // NB*NHW
#define NHP 58            // padded dim
#define EPSV 1e-5f
#define BUFS 20480        // shorts per LDS buffer: Al 4096 | Bl 16384
#define TOFN 451584       // NB*18*NHW floats

typedef float f32x4 __attribute__((ext_vector_type(4)));
typedef __bf16 bf16x8 __attribute__((ext_vector_type(8)));
typedef _Float16 f16x8 __attribute__((ext_vector_type(8)));

__device__ __forceinline__ unsigned short f2b(float f) {   // RNE -> bf16
  unsigned int u = __float_as_uint(f);
  u += 0x7FFFu + ((u >> 16) & 1u);
  return (unsigned short)(u >> 16);
}
__device__ __forceinline__ unsigned short f2h(float f) {   // RNE -> fp16
  return __half_as_ushort(__float2half(f));
}
// barrier WITHOUT vmcnt drain (gemm_off only)
__device__ __forceinline__ void soft_barrier() {
  __builtin_amdgcn_s_waitcnt(0xC07F);   // vmcnt=63, expcnt=7, lgkmcnt=0
  __builtin_amdgcn_s_barrier();
}
// async global->LDS DMA, 16B per lane; LDS dest = wave-uniform base + lane*16
__device__ __forceinline__ void dma16(const unsigned short* g, unsigned short* l) {
  __builtin_amdgcn_global_load_lds(
      (const __attribute__((address_space(1))) unsigned int*)g,
      (__attribute__((address_space(3))) unsigned int*)l,
      16, 0, 0);
}
// packed fp16 bilinear: w00*c00 + w01*c01 + w10*c10 + w11*c11 (2 lanes/op)
__device__ __forceinline__ unsigned int bil2(
    unsigned int c00, unsigned int c01, unsigned int c10, unsigned int c11,
    __half2 W00, __half2 W01, __half2 W10, __half2 W11) {
  __half2 v = __hmul2(W00, *(__half2*)&c00);
  v = __hfma2(W01, *(__half2*)&c01, v);
  v = __hfma2(W10, *(__half2*)&c10, v);
  v = __hfma2(W11, *(__half2*)&c11, v);
  return *(unsigned int*)&v;
}

// ---------------------------------------------------------------------------
// PREP (fused): blocks [0,228): borders+tof zero; [228,1796): prep_x;
// [1796,6692): weight preps. All branches block-uniform.
// ---------------------------------------------------------------------------
__global__ __launch_bounds__(256) void prep_fused(
    const float* __restrict__ x,  unsigned short* __restrict__ xbp,
    unsigned short* __restrict__ t1b, float* __restrict__ tof,
    const float* __restrict__ w1, const float* __restrict__ w2,
    const float* __restrict__ ow,
    unsigned short* __restrict__ w1p, unsigned short* __restrict__ w2p,
    unsigned short* __restrict__ w3p)
{
  __shared__ float T[64][65];
  const int bid = blockIdx.x;
  const int tid = threadIdx.x;

  if (bid < 228) {
    // ---- borders + tof zero ----
    int i = bid*256 + tid;                       // 58368 exact
    int q = i & 31; int pid = i >> 5;
    int b = pid / 228, j = pid % 228;
    int y, xx;
    if (j < 58)       { y = 0;  xx = j; }
    else if (j < 116) { y = 57; xx = j - 58; }
    else { int jj = j - 116; y = 1 + (jj >> 1); xx = (jj & 1) * 57; }
    size_t addr = ((size_t)(b*NHP + y)*NHP + xx)*256 + q*8;
    uint4 z = make_uint4(0u,0u,0u,0u);
    *(uint4*)(xbp + addr) = z;
    *(uint4*)(t1b + addr) = z;
    int zi = i*8;                                // 56448*8 = 451584 exact
    if (zi < TOFN) {
      *(float4*)(tof + zi)     = make_float4(0.f,0.f,0.f,0.f);
      *(float4*)(tof + zi + 4) = make_float4(0.f,0.f,0.f,0.f);
    }
  } else if (bid < 1796) {
    // ---- prep_x: x NCHW fp32 -> xbp padded NHWC bf16 (interior) ----
    const int j2   = bid - 228;                  // 0..1567 = 392*4
    const int pxt  = (j2 % 392) * 64;            // never crosses b
    const int cg   = (j2 / 392) * 64;
    const int b    = pxt / NHW;
    const int rem0 = pxt % NHW;
    const int pl   = tid & 63;
    const int c0   = tid >> 6;
    const float* src = x + (size_t)b*NCHW + rem0;
    #pragma unroll
    for (int it = 0; it < 16; ++it) {
      int c = c0 + it*4;
      T[c][pl] = src[(size_t)(cg + c)*NHW + pl];
    }
    __syncthreads();
    const int pr = tid >> 5;
    const int cp = tid & 31;
    #pragma unroll
    for (int it = 0; it < 8; ++it) {
      int pxl = pr + it*8;
      int rem = rem0 + pxl;
      int ho = rem / NW, wo = rem % NW;
      unsigned int pk = ((unsigned int)f2b(T[cp*2+1][pxl]) << 16) | (unsigned int)f2b(T[cp*2][pxl]);
      *(unsigned int*)(xbp + ((size_t)(b*NHP + ho + 1)*NHP + (wo + 1))*256 + cg + cp*2) = pk;
    }
  } else {
    // ---- weight preps: w1->bf16, w2/ow->fp16 ----
    int i = (bid - 1796)*256 + tid;              // 0..1253375
    if (i < 589824) {
      int co = i / 2304, r = i % 2304, k = r >> 8, ci = r & 255;
      w1p[i] = f2b(w1[((size_t)co*256 + ci)*9 + k]);
    } else if (i < 1179648) {
      int j = i - 589824;
      int co = j / 2304, r = j % 2304, k = r >> 8, ci = r & 255;
      w2p[j] = f2h(w2[((size_t)co*256 + ci)*9 + k]);
    } else {
      int j = i - 1179648;                       // < 73728
      int co = j / 2304, r = j % 2304, k = r >> 8, ci = r & 255;
      w3p[j] = (co < 18) ? f2h(ow[((size_t)co*256 + ci)*9 + k]) : (unsigned short)0;
    }
  }
}

// ---------------------------------------------------------------------------
// GEMM1: conv3x3 + BN + ReLU -> t1b padded NHWC fp16  (verified r9 form)
// BM=64 BN=256 BK=64, 512 thr = 8 waves; full global_load_lds DMA staging,
// LDS dbuf, 1 __syncthreads/round; grid 392, batch-per-XCD swizzle.
// ---------------------------------------------------------------------------
__global__ __launch_bounds__(512, 4) void gemm_conv1(
    const unsigned short* __restrict__ xbp, const unsigned short* __restrict__ w1p,
    const float* __restrict__ gam, const float* __restrict__ bet,
    const float* __restrict__ mu,  const float* __restrict__ var,
    unsigned short* __restrict__ t1b)
{
  __shared__ unsigned short SMEM[2*BUFS];    // 80KB: two of (Al 4096 | Bl 16384)

  const int bx   = blockIdx.x;
  const int nbx  = (bx & 7)*49 + (bx >> 3);   // 392 = 8*49, batch-per-XCD
  const int m0   = nbx * 64;
  const int t    = threadIdx.x;
  const int lane = t & 63;
  const int wv   = t >> 6;
  const int wvM  = wv & 1;
  const int wvN  = wv >> 1;
  const int quad = lane >> 4;
  const int l15  = lane & 15;

  const int srow = t >> 3;               // = wv*8 + (lane>>3), 0..63
  const int seg  = t & 7;                // = lane&7
  const int swz8 = ((seg ^ (srow & 7))*8);   // swizzled sub-block (shorts)
  const int px  = m0 + srow;
  const int b   = px / NHW, rem = px % NHW;
  const int ho  = rem / NW, wo = rem % NW;
  const unsigned int pbaseA = ((unsigned int)(b*NHP + ho)*NHP + wo)*256u + (unsigned int)swz8;
  const int rowB0 = wv*32 + (lane >> 3);
  const unsigned int bswz = (unsigned int)(((lane & 7) ^ (lane >> 3))*8);
  const int chA = wv*512;                // A LDS chunk base (shorts)

  f32x4 acc[2][4];
  #pragma unroll
  for (int i = 0; i < 2; ++i)
    #pragma unroll
    for (int j = 0; j < 4; ++j) acc[i][j] = (f32x4)(0.f);

  {   // prologue: DMA r=0 into buf0
    dma16(xbp + pbaseA, &SMEM[chA]);
    #pragma unroll
    for (int j = 0; j < 4; ++j)
      dma16(w1p + (size_t)(rowB0 + j*8)*2304 + bswz, &SMEM[4096 + (wv*4 + j)*512]);
    __syncthreads();
  }

  for (int r = 0; r < 36; ++r) {
    unsigned short* Ac = SMEM + (r & 1)*BUFS;
    unsigned short* Bc = Ac + 4096;
    unsigned short* An = SMEM + ((r + 1) & 1)*BUFS;
    unsigned short* Bn = An + 4096;
    if (r < 35) {   // DMA r+1 into next buffer (tail guard: r=35 issues nothing)
      const int rn = r + 1;
      const int kn = rn >> 2, cicn = rn & 3;
      const int kyn = kn/3, kxn = kn - kyn*3;
      const unsigned int koff = (unsigned int)((kyn*NHP + kxn)*256 + cicn*64);
      dma16(xbp + pbaseA + koff, &An[chA]);
      const unsigned int rb = (unsigned int)(rn*64);
      #pragma unroll
      for (int j = 0; j < 4; ++j)
        dma16(w1p + (size_t)(rowB0 + j*8)*2304 + rb + bswz, &Bn[(wv*4 + j)*512]);
    }
    // MFMA from current buffer
    #pragma unroll
    for (int kk = 0; kk < 2; ++kk) {
      const int s8 = (kk*4 + quad) ^ (l15 & 7);
      bf16x8 af[2], bfr[4];
      #pragma unroll
      for (int mt = 0; mt < 2; ++mt)
        af[mt] = *(const bf16x8*)(&Ac[(wvM*32 + mt*16 + l15)*64 + s8*8]);
      #pragma unroll
      for (int nt = 0; nt < 4; ++nt)
        bfr[nt] = *(const bf16x8*)(&Bc[(wvN*64 + nt*16 + l15)*64 + s8*8]);
      #pragma unroll
      for (int mt = 0; mt < 2; ++mt)
        #pragma unroll
        for (int nt = 0; nt < 4; ++nt)
          acc[mt][nt] = __builtin_amdgcn_mfma_f32_16x16x32_bf16(af[mt], bfr[nt], acc[mt][nt], 0, 0, 0);
    }
    __syncthreads();   // drains DMA (vmcnt 0) + makes next buffer visible
  }

  // epilogue: BN+ReLU -> per-wave bounce (32px x 72 shorts) -> padded t1b (fp16)
  unsigned short* Sw = SMEM + wv*2304;
  #pragma unroll
  for (int nt = 0; nt < 4; ++nt) {
    const int co = wvN*64 + nt*16 + l15;
    const float inv  = gam[co] * rsqrtf(var[co] + EPSV);
    const float beta = bet[co] - mu[co]*inv;
    #pragma unroll
    for (int mt = 0; mt < 2; ++mt) {
      #pragma unroll
      for (int rr = 0; rr < 4; ++rr) {
        const int pxl = mt*16 + quad*4 + rr;
        float val = acc[mt][nt][rr]*inv + beta;
        val = val > 0.f ? val : 0.f;
        Sw[pxl*72 + nt*16 + l15] = f2h(val);
      }
    }
  }
  #pragma unroll
  for (int i = 0; i < 4; ++i) {
    const int pxl = (lane >> 3) + 8*i;
    const int sc  = lane & 7;
    uint4 q = *(const uint4*)(&Sw[pxl*72 + sc*8]);
    const int pg = m0 + wvM*32 + pxl;
    const int bb = pg / NHW, rm = pg % NHW;
    const int hh = rm / NW, ww = rm % NW;
    *(uint4*)(t1b + ((size_t)(bb*NHP + hh + 1)*NHP + ww + 1)*256 + wvN*64 + sc*8) = q;
  }
}

// ---------------------------------------------------------------------------
// GEMM-OFF: offset conv (fp16 operands), split-K x4, atomicAdd into toff
// (unchanged, verified r9)
// ---------------------------------------------------------------------------
__global__ __launch_bounds__(256, 8) void gemm_off(
    const unsigned short* __restrict__ t1b, const unsigned short* __restrict__ w3p,
    const float* __restrict__ ob, float* __restrict__ toff)
{
  __shared__ unsigned short Al[4096];   // 64x64
  __shared__ unsigned short Bl[2048];   // 32x64

  const int bx  = blockIdx.x;
  const int nbx = (bx & 7)*49 + (bx >> 3);
  const int m0  = nbx * 64;
  const int kc = blockIdx.y;            // K chunk 0..3
  const int t    = threadIdx.x;
  const int lane = t & 63;
  const int wv   = t >> 6;
  const int quad = lane >> 4;
  const int l15  = lane & 15;

  const int arow = t >> 2;      // 0..63
  const int as4  = t & 3;
  const int axor = arow & 7;
  const int pxa  = m0 + arow;
  const int ba   = pxa / NHW, rema = pxa % NHW;
  const unsigned int pbase = ((unsigned int)(ba*NHP + rema/NW)*NHP + rema%NW)*256u;

  const int brow = t >> 3;      // 0..31
  const int bs   = t & 7;

  f32x4 acc[2];
  #pragma unroll
  for (int nt = 0; nt < 2; ++nt) {
    float init = 0.f;
    if (kc == 0) { int co = nt*16 + l15; init = (co < 18) ? ob[co] : 0.f; }
    acc[nt] = (f32x4)(init);
  }

  uint4 pA0, pA1, pB;
  {   // prefetch first round r = kc*9
    const int r = kc*9, k = r >> 2, cic = r & 3;
    const int ky = k/3, kx = k - ky*3;
    const unsigned int base = pbase + (unsigned int)((ky*NHP + kx)*256 + cic*64);
    pA0 = *(const uint4*)(t1b + base + as4*8);
    pA1 = *(const uint4*)(t1b + base + (as4+4)*8);
    pB  = *(const uint4*)(w3p + (size_t)brow*2304 + r*64 + bs*8);
  }

  for (int rr = 0; rr < 9; ++rr) {
    const int r = kc*9 + rr;
    __syncthreads();
    *(uint4*)(&Al[arow*64 + ((as4     ^ axor)*8)]) = pA0;
    *(uint4*)(&Al[arow*64 + (((as4+4) ^ axor)*8)]) = pA1;
    *(uint4*)(&Bl[brow*64 + ((bs ^ (brow & 7))*8)]) = pB;
    {
      const int rn = (rr < 8) ? r + 1 : r;
      const int kn = rn >> 2, cicn = rn & 3;
      const int kyn = kn/3, kxn = kn - kyn*3;
      const unsigned int base = pbase + (unsigned int)((kyn*NHP + kxn)*256 + cicn*64);
      pA0 = *(const uint4*)(t1b + base + as4*8);
      pA1 = *(const uint4*)(t1b + base + (as4+4)*8);
      pB  = *(const uint4*)(w3p + (size_t)brow*2304 + rn*64 + bs*8);
    }
    soft_barrier();
    #pragma unroll
    for (int kk = 0; kk < 2; ++kk) {
      const int s8 = (kk*4 + quad) ^ (l15 & 7);
      f16x8 af = *(const f16x8*)(&Al[(wv*16 + l15)*64 + s8*8]);
      #pragma unroll
      for (int nt = 0; nt < 2; ++nt) {
        f16x8 bfr = *(const f16x8*)(&Bl[(nt*16 + l15)*64 + s8*8]);
        acc[nt] = __builtin_amdgcn_mfma_f32_16x16x32_f16(af, bfr, acc[nt], 0, 0, 0);
      }
    }
  }
  #pragma unroll
  for (int nt = 0; nt < 2; ++nt) {
    const int co = nt*16 + l15;
    if (co < 18) {
      #pragma unroll
      for (int rr2 = 0; rr2 < 4; ++rr2) {
        const int pg = m0 + wv*16 + quad*4 + rr2;
        const int bb = pg / NHW, rm = pg % NHW;
        atomicAdd(&toff[(size_t)bb*(18*NHW) + (size_t)co*NHW + rm], acc[nt][rr2]);
      }
    }
  }
}

// ---------------------------------------------------------------------------
// GEMM2: deform_conv + BN + residual + ReLU -> out NCHW fp32  (verified r9)
// BM=64 BN=256 BK=64, 512 thr = 8 waves; B via global_load_lds DMA,
// corners via VGPR gather + packed fp16 bilinear. LDS dbuf, 1 sync/round.
// ---------------------------------------------------------------------------
__global__ __launch_bounds__(512, 4) void gemm_deform(
    const unsigned short* __restrict__ t1b, const unsigned short* __restrict__ w2p,
    const float* __restrict__ toff, const float* __restrict__ xres,
    const float* __restrict__ gam, const float* __restrict__ bet,
    const float* __restrict__ mu,  const float* __restrict__ var,
    float* __restrict__ outp)
{
  __shared__ unsigned short SMEM[2*BUFS];    // 80KB

  const int bid  = blockIdx.x;
  const int nb   = (bid & 7)*49 + (bid >> 3);   // 392 = 8*49
  const int m0   = nb * 64;
  const int t    = threadIdx.x;
  const int lane = t & 63;
  const int wv   = t >> 6;
  const int wvM  = wv & 1;
  const int wvN  = wv >> 1;
  const int quad = lane >> 4;
  const int l15  = lane & 15;

  const int srow = t >> 3;     // 0..63
  const int seg  = t & 7;
  const int sxor = srow & 7;
  const int px   = m0 + srow;
  const int b    = px / NHW, rem = px % NHW;
  const int ho   = rem / NW, wo = rem % NW;
  const int obb  = b*(18*NHW) + rem;
  const unsigned int prowb = (unsigned int)(b*NHP);

  // B DMA mapping (identical LDS image to the verified swizzled layout)
  const int rowB0 = wv*32 + (lane >> 3);
  const unsigned int bswz = (unsigned int)(((lane & 7) ^ (lane >> 3))*8);

  f32x4 acc[2][4];
  #pragma unroll
  for (int i = 0; i < 2; ++i)
    #pragma unroll
    for (int j = 0; j < 4; ++j) acc[i][j] = (f32x4)(0.f);

  // bilinear coord state for the k being issued (weights as packed half2)
  unsigned int o00, o01, o10, o11;
  __half2 W00, W01, W10, W11;
#define COORDS(KK) {                                                   \
    const int ky_ = (KK)/3, kx_ = (KK) - ky_*3;                        \
    const float offy = toff[obb + (KK)*NHW];                           \
    const float offx = toff[obb + (9+(KK))*NHW];                       \
    const float yf = (float)(ho - 1 + ky_) + offy;                     \
    const float xf = (float)(wo - 1 + kx_) + offx;                     \
    const float y0f = floorf(yf), x0f = floorf(xf);                    \
    const float ty = yf - y0f,   tx = xf - x0f;                        \
    const int y0p = (int)y0f + 1, x0p = (int)x0f + 1;                  \
    const int cy0 = min(max(y0p,   0), NHP-1);                         \
    const int cy1 = min(max(y0p+1, 0), NHP-1);                         \
    const int cx0 = min(max(x0p,   0), NHP-1);                         \
    const int cx1 = min(max(x0p+1, 0), NHP-1);                         \
    W00 = __float2half2_rn((1.f-ty)*(1.f-tx));                         \
    W01 = __float2half2_rn((1.f-ty)*tx);                               \
    W10 = __float2half2_rn(ty*(1.f-tx));                               \
    W11 = __float2half2_rn(ty*tx);                                     \
    o00 = ((prowb + cy0)*NHP + cx0)*256u + seg*8u;                     \
    o01 = ((prowb + cy0)*NHP + cx1)*256u + seg*8u;                     \
    o10 = ((prowb + cy1)*NHP + cx0)*256u + seg*8u;                     \
    o11 = ((prowb + cy1)*NHP + cx1)*256u + seg*8u;                     \
  }

// packed-fp16 bilinear combine of 4 corner uint4 -> one uint4 -> LDS (swizzled)
#define PACKW(DST) {                                                            \
    uint4 res;                                                                  \
    res.x = bil2(pc00.x, pc01.x, pc10.x, pc11.x, W00, W01, W10, W11);           \
    res.y = bil2(pc00.y, pc01.y, pc10.y, pc11.y, W00, W01, W10, W11);           \
    res.z = bil2(pc00.z, pc01.z, pc10.z, pc11.z, W00, W01, W10, W11);           \
    res.w = bil2(pc00.w, pc01.w, pc10.w, pc11.w, W00, W01, W10, W11);           \
    *(uint4*)(&(DST)[srow*64 + ((seg ^ sxor)*8)]) = res;                        \
  }

#define ISSUEC(RN) {                                                           \
    const unsigned int cio_ = (unsigned int)(((RN) & 3)*64);                   \
    pc00 = *(const uint4*)(t1b + o00 + cio_);                                  \
    pc01 = *(const uint4*)(t1b + o01 + cio_);                                  \
    pc10 = *(const uint4*)(t1b + o10 + cio_);                                  \
    pc11 = *(const uint4*)(t1b + o11 + cio_);                                  \
  }

  uint4 pc00, pc01, pc10, pc11;

  COORDS(0);
  {   // prologue: corners(0) -> pack into buf0; DMA B(0) -> buf0; issue corners(1)
    ISSUEC(0);
    #pragma unroll
    for (int j = 0; j < 4; ++j)
      dma16(w2p + (size_t)(rowB0 + j*8)*2304 + bswz, &SMEM[4096 + (wv*4 + j)*512]);
    PACKW(SMEM);
    ISSUEC(1);
    __syncthreads();
  }

  for (int r = 0; r < 36; ++r) {
    unsigned short* Ac = SMEM + (r & 1)*BUFS;
    unsigned short* Bc = Ac + 4096;
    unsigned short* An = SMEM + ((r + 1) & 1)*BUFS;
    unsigned short* Bn = An + 4096;
    // pack prefetched corners(r+1) -> next A buffer (weights for k=(r+1)>>2 live)
    if (r < 35) PACKW(An);
    if (r < 35) {   // DMA B(r+1) -> next B buffer (tail guard)
      const unsigned int rb = (unsigned int)((r + 1)*64);
      #pragma unroll
      for (int j = 0; j < 4; ++j)
        dma16(w2p + (size_t)(rowB0 + j*8)*2304 + rb + bswz, &Bn[(wv*4 + j)*512]);
    }
    // coords for the k of round r+2 (AFTER pack used old weights)
    if ((r & 3) == 2 && r < 34) COORDS((r + 2) >> 2);
    if (r < 34) {   // issue corners(r+2) (tail guard)
      ISSUEC(r + 2);
    }
    // MFMA from current buffer (fp16 operands)
    #pragma unroll
    for (int kk = 0; kk < 2; ++kk) {
      const int s8 = (kk*4 + quad) ^ (l15 & 7);
      f16x8 af[2], bfr[4];
      #pragma unroll
      for (int mt = 0; mt < 2; ++mt)
        af[mt] = *(const f16x8*)(&Ac[(wvM*32 + mt*16 + l15)*64 + s8*8]);
      #pragma unroll
      for (int nt = 0; nt < 4; ++nt)
        bfr[nt] = *(const f16x8*)(&Bc[(wvN*64 + nt*16 + l15)*64 + s8*8]);
      #pragma unroll
      for (int mt = 0; mt < 2; ++mt)
        #pragma unroll
        for (int nt = 0; nt < 4; ++nt)
          acc[mt][nt] = __builtin_amdgcn_mfma_f32_16x16x32_f16(af[mt], bfr[nt], acc[mt][nt], 0, 0, 0);
    }
    __syncthreads();   // drains B-DMA + corner loads, publishes next buffers
  }
#undef ISSUEC
#undef PACKW
#undef COORDS

  // epilogue: per-wave f32 bounce (32px x 33), 2 co-halves -> coalesced NCHW
  float* Sl = (float*)SMEM + wv*1056;
  const int pxl_r = lane & 31;
  const int csel  = lane >> 5;
  const int pg    = m0 + wvM*32 + pxl_r;
  const int bo    = pg / NHW, remo = pg % NHW;
  const size_t obase = (size_t)bo*NCHW + remo;
  #pragma unroll
  for (int h = 0; h < 2; ++h) {
    #pragma unroll
    for (int nt2 = 0; nt2 < 2; ++nt2) {
      const int nt = h*2 + nt2;
      #pragma unroll
      for (int mt = 0; mt < 2; ++mt) {
        #pragma unroll
        for (int rr = 0; rr < 4; ++rr) {
          const int pxl = mt*16 + quad*4 + rr;
          Sl[pxl*33 + nt2*16 + l15] = acc[mt][nt][rr];
        }
      }
    }
    #pragma unroll
    for (int j = 0; j < 16; ++j) {
      const int col = csel*16 + j;
      const int co  = wvN*64 + h*32 + col;
      const float inv  = gam[co] * rsqrtf(var[co] + EPSV);
      const float beta = bet[co] - mu[co]*inv;
      const size_t off = obase + (size_t)co*NHW;
      float val = Sl[pxl_r*33 + col];
      float o = val*inv + beta + xres[off];
      outp[off] = o > 0.f ? o : 0.f;
    }
  }
}

extern "C" void kernel_launch(void* const* d_in, const int* in_sizes, int n_in,
                              void* d_out, int out_size, void* d_ws, size_t ws_size,
                              hipStream_t stream) {
  const float* x   = (const float*)d_in[0];
  const float* w1  = (const float*)d_in[1];
  const float* g1  = (const float*)d_in[2];
  const float* b1  = (const float*)d_in[3];
  const float* m1  = (const float*)d_in[4];
  const float* v1  = (const float*)d_in[5];
  const float* ow  = (const float*)d_in[6];
  const float* ob  = (const float*)d_in[7];
  const float* w2  = (const float*)d_in[8];
  const float* g2  = (const float*)d_in[9];
  const float* b2  = (const float*)d_in[10];
  const float* m2  = (const float*)d_in[11];
  const float* v2  = (const float*)d_in[12];
  float* out = (float*)d_out;

  const size_t PADSZ = (size_t)NB*NHP*NHP*256;
  unsigned short* xbp = (unsigned short*)d_ws;
  unsigned short* t1b = xbp + PADSZ;
  float*          tof = (float*)(t1b + PADSZ);
  unsigned short* w1p = (unsigned short*)(tof + (size_t)NB*18*NHW);
  unsigned short* w2p = w1p + (size_t)589824;
  unsigned short* w3p = w2p + (size_t)589824;

  prep_fused<<<6692, 256, 0, stream>>>(x, xbp, t1b, tof, w1, w2, ow, w1p, w2p, w3p);

  gemm_conv1<<<392, 512, 0, stream>>>(xbp, w1p, g1, b1, m1, v1, t1b);
  dim3 go(392, 4, 1);
  gemm_off<<<go, 256, 0, stream>>>(t1b, w3p, ob, tof);
  gemm_deform<<<392, 512, 0, stream>>>(t1b, w2p, tof, x, g2, b2, m2, v2, out);
}